// Round 10
// baseline (181.150 us; speedup 1.0000x reference)
//
#include <hip/hip_runtime.h>

// ---------------- problem constants ----------------
#define NNODES 50000
#define INC 100
#define HIDC 128
#define OUTC 40
#define NBUCKET 8
#define BUCKET_SZ ((NNODES + NBUCKET - 1) / NBUCKET)   // 6250
#define BIN_BLOCKS 1024
#define SB_CHUNKS 64
#define CAP 200000   // per-bucket pair capacity (mean 100K, sigma ~300 -> safe)

typedef short bf16x8 __attribute__((ext_vector_type(8)));
typedef float f32x4 __attribute__((ext_vector_type(4)));

// bf16 helpers (RNE pack, shift unpack)
__device__ __forceinline__ unsigned short f2bf(float f) {
    unsigned int u = __float_as_uint(f);
    unsigned int r = (u + 0x7FFFu + ((u >> 16) & 1u)) >> 16;
    return (unsigned short)r;
}
__device__ __forceinline__ unsigned int pack2(float a, float b) {
    return (unsigned int)f2bf(a) | ((unsigned int)f2bf(b) << 16);
}
__device__ __forceinline__ float4 bf4(uint2 a) {
    return make_float4(__uint_as_float(a.x << 16), __uint_as_float(a.x & 0xFFFF0000u),
                       __uint_as_float(a.y << 16), __uint_as_float(a.y & 0xFFFF0000u));
}

// ================= fused prep: x->bf16 + 4 weight transposes =================
__global__ __launch_bounds__(256) void prep_all(const float2* __restrict__ x2,
                                                unsigned int* __restrict__ xh, int n2,
                                                const float* __restrict__ W1a,
                                                unsigned short* __restrict__ Wt1a,
                                                const float* __restrict__ W1b,
                                                unsigned short* __restrict__ Wt1b,
                                                const float* __restrict__ W2a,
                                                unsigned short* __restrict__ Wt2a,
                                                const float* __restrict__ W2b,
                                                unsigned short* __restrict__ Wt2b) {
    int i = blockIdx.x * 256 + threadIdx.x;
    if (i < n2) {
        float2 v = x2[i];
        xh[i] = pack2(v.x, v.y);
        return;
    }
    i -= n2;
    if (i < 128 * 128) {  // Wt1a[j][128], W1a is [100][128]
        int j = i >> 7, k = i & 127;
        Wt1a[i] = f2bf((k < INC) ? W1a[k * HIDC + j] : 0.f);
        return;
    }
    i -= 128 * 128;
    if (i < 128 * 128) {  // Wt1b[j][128], W1b is [128][128]
        int j = i >> 7, k = i & 127;
        Wt1b[i] = f2bf(W1b[k * HIDC + j]);
        return;
    }
    i -= 128 * 128;
    if (i < 48 * 128) {  // Wt2a[j][128], W2a is [128][40]
        int j = i >> 7, k = i & 127;
        Wt2a[i] = f2bf((j < OUTC) ? W2a[k * OUTC + j] : 0.f);
        return;
    }
    i -= 48 * 128;
    if (i < 48 * 64) {  // Wt2b[j][64], W2b is [40][40]
        int j = i >> 6, k = i & 63;
        Wt2b[i] = f2bf((j < OUTC && k < OUTC) ? W2b[k * OUTC + j] : 0.f);
        return;
    }
}

// ================= bin + count: deg atomics + compact (d<<16|s) pairs per bucket =================
__global__ __launch_bounds__(256) void bin_count(const int* __restrict__ src,
                                                 const int* __restrict__ dst,
                                                 int* __restrict__ deg,
                                                 int* __restrict__ bcnt,
                                                 unsigned int* __restrict__ pairs, int E) {
    __shared__ int bcount[NBUCKET];
    __shared__ int bbase[NBUCKET];
    __shared__ int bpos[NBUCKET];
    int t = threadIdx.x;
    if (t < NBUCKET) bcount[t] = 0;
    __syncthreads();
    int lo = (int)((long long)E * blockIdx.x / BIN_BLOCKS);
    int hi = (int)((long long)E * (blockIdx.x + 1) / BIN_BLOCKS);
    for (int e = lo + t; e < hi; e += 256) {
        int d = __builtin_nontemporal_load(&dst[e]);
        atomicAdd(&deg[d], 1);
        atomicAdd(&bcount[d / BUCKET_SZ], 1);
    }
    __syncthreads();
    if (t < NBUCKET) {
        bbase[t] = atomicAdd(&bcnt[t], bcount[t]);
        bpos[t] = 0;
    }
    __syncthreads();
    for (int e = lo + t; e < hi; e += 256) {
        int d = __builtin_nontemporal_load(&dst[e]);
        int s = __builtin_nontemporal_load(&src[e]);
        int b = d / BUCKET_SZ;
        int rk = atomicAdd(&bpos[b], 1);
        pairs[(size_t)b * CAP + bbase[b] + rk] = ((unsigned int)d << 16) | (unsigned int)s;
    }
}

// ================= scans =================
__global__ __launch_bounds__(256) void scan_pass1(const int* __restrict__ deg,
                                                  int* __restrict__ lexcl,
                                                  int* __restrict__ blk_sums, int n) {
    __shared__ int wsum[4];
    int base = blockIdx.x * 1024;
    int t = threadIdx.x;
    int i0 = base + t * 4;
    int a = (i0 + 0 < n) ? deg[i0 + 0] : 0;
    int b = (i0 + 1 < n) ? deg[i0 + 1] : 0;
    int c = (i0 + 2 < n) ? deg[i0 + 2] : 0;
    int d = (i0 + 3 < n) ? deg[i0 + 3] : 0;
    int s4 = a + b + c + d;
    int lane = t & 63, w = t >> 6;
    int incl = s4;
#pragma unroll
    for (int off = 1; off < 64; off <<= 1) {
        int u = __shfl_up(incl, off);
        if (lane >= off) incl += u;
    }
    if (lane == 63) wsum[w] = incl;
    __syncthreads();
    int wbase = 0;
#pragma unroll
    for (int j = 0; j < 4; ++j)
        if (j < w) wbase += wsum[j];
    int excl = wbase + incl - s4;
    if (i0 + 0 < n) lexcl[i0 + 0] = excl;
    if (i0 + 1 < n) lexcl[i0 + 1] = excl + a;
    if (i0 + 2 < n) lexcl[i0 + 2] = excl + a + b;
    if (i0 + 3 < n) lexcl[i0 + 3] = excl + a + b + c;
    if (t == 255) blk_sums[blockIdx.x] = wbase + incl;
}

__global__ __launch_bounds__(64) void scan_pass2(int* __restrict__ blk_sums, int nb,
                                                 int* __restrict__ offs_end) {
    int lane = threadIdx.x;
    int v = (lane < nb) ? blk_sums[lane] : 0;
    int incl = v;
#pragma unroll
    for (int off = 1; off < 64; off <<= 1) {
        int u = __shfl_up(incl, off);
        if (lane >= off) incl += u;
    }
    if (lane < nb) blk_sums[lane] = incl - v;
    if (lane == 63) offs_end[0] = incl;
}

__global__ __launch_bounds__(256) void scan_pass3(const int* __restrict__ lexcl,
                                                  const int* __restrict__ blk_sums,
                                                  int* __restrict__ offs,
                                                  int* __restrict__ cursor, int n) {
    int i = blockIdx.x * 256 + threadIdx.x;
    if (i < n) {
        int v = lexcl[i] + blk_sums[i >> 10];
        offs[i] = v;
        cursor[i] = v;
    }
}

// ================= bucket-affine scatter from compact pairs into ushort csr =================
// Per XCD working set: ~400KB pair stream + ~400KB csr + 25KB cursor -> L2-resident.
__global__ __launch_bounds__(256) void scatter_pairs(const unsigned int* __restrict__ pairs,
                                                     const int* __restrict__ bcnt,
                                                     int* __restrict__ cursor,
                                                     unsigned short* __restrict__ csr) {
    int b = blockIdx.x & (NBUCKET - 1);
    int chunk = blockIdx.x >> 3;
    int cnt = bcnt[b];
    int lo = (int)((long long)cnt * chunk / SB_CHUNKS);
    int hi = (int)((long long)cnt * (chunk + 1) / SB_CHUNKS);
    const unsigned int* P = pairs + (size_t)b * CAP;
    for (int i = lo + (int)threadIdx.x; i < hi; i += 256) {
        unsigned int pr = __builtin_nontemporal_load(&P[i]);
        int d = (int)(pr >> 16);
        int pos = atomicAdd(&cursor[d], 1);
        csr[pos] = (unsigned short)(pr & 0xFFFFu);
    }
}

// ================= layer-1 aggregation: bf16 gather, fp32 self+acc, bf16 out [N][128] padded =================
__global__ __launch_bounds__(256) void agg_wide_bf(const float4* __restrict__ self,
                                                   const uint2* __restrict__ featbf,
                                                   const int* __restrict__ offs,
                                                   const unsigned short* __restrict__ csr,
                                                   unsigned short* __restrict__ Abf, int N) {
    constexpr int C4 = 25;
    int node = blockIdx.x * 8 + (threadIdx.x >> 5);
    int l = threadIdx.x & 31;
    if (node >= N) return;
    if (l >= C4) {  // zero-pad cols 100..127
        *reinterpret_cast<uint2*>(&Abf[(size_t)node * 128 + l * 4]) = make_uint2(0u, 0u);
        return;
    }
    int s = offs[node], e = offs[node + 1];
    float4 acc = self[(size_t)node * C4 + l];
    int i = s;
    for (; i + 8 <= e; i += 8) {
        int n0 = (int)__builtin_nontemporal_load(&csr[i + 0]);
        int n1 = (int)__builtin_nontemporal_load(&csr[i + 1]);
        int n2 = (int)__builtin_nontemporal_load(&csr[i + 2]);
        int n3 = (int)__builtin_nontemporal_load(&csr[i + 3]);
        int n4 = (int)__builtin_nontemporal_load(&csr[i + 4]);
        int n5 = (int)__builtin_nontemporal_load(&csr[i + 5]);
        int n6 = (int)__builtin_nontemporal_load(&csr[i + 6]);
        int n7 = (int)__builtin_nontemporal_load(&csr[i + 7]);
        float4 v0 = bf4(featbf[(size_t)n0 * C4 + l]);
        float4 v1 = bf4(featbf[(size_t)n1 * C4 + l]);
        float4 v2 = bf4(featbf[(size_t)n2 * C4 + l]);
        float4 v3 = bf4(featbf[(size_t)n3 * C4 + l]);
        float4 v4 = bf4(featbf[(size_t)n4 * C4 + l]);
        float4 v5 = bf4(featbf[(size_t)n5 * C4 + l]);
        float4 v6 = bf4(featbf[(size_t)n6 * C4 + l]);
        float4 v7 = bf4(featbf[(size_t)n7 * C4 + l]);
        acc.x += ((v0.x + v1.x) + (v2.x + v3.x)) + ((v4.x + v5.x) + (v6.x + v7.x));
        acc.y += ((v0.y + v1.y) + (v2.y + v3.y)) + ((v4.y + v5.y) + (v6.y + v7.y));
        acc.z += ((v0.z + v1.z) + (v2.z + v3.z)) + ((v4.z + v5.z) + (v6.z + v7.z));
        acc.w += ((v0.w + v1.w) + (v2.w + v3.w)) + ((v4.w + v5.w) + (v6.w + v7.w));
    }
    for (; i + 4 <= e; i += 4) {
        int n0 = (int)__builtin_nontemporal_load(&csr[i + 0]);
        int n1 = (int)__builtin_nontemporal_load(&csr[i + 1]);
        int n2 = (int)__builtin_nontemporal_load(&csr[i + 2]);
        int n3 = (int)__builtin_nontemporal_load(&csr[i + 3]);
        float4 v0 = bf4(featbf[(size_t)n0 * C4 + l]);
        float4 v1 = bf4(featbf[(size_t)n1 * C4 + l]);
        float4 v2 = bf4(featbf[(size_t)n2 * C4 + l]);
        float4 v3 = bf4(featbf[(size_t)n3 * C4 + l]);
        acc.x += (v0.x + v1.x) + (v2.x + v3.x);
        acc.y += (v0.y + v1.y) + (v2.y + v3.y);
        acc.z += (v0.z + v1.z) + (v2.z + v3.z);
        acc.w += (v0.w + v1.w) + (v2.w + v3.w);
    }
    for (; i < e; ++i) {
        int sn = (int)__builtin_nontemporal_load(&csr[i]);
        float4 v = bf4(featbf[(size_t)sn * C4 + l]);
        acc.x += v.x; acc.y += v.y; acc.z += v.z; acc.w += v.w;
    }
    *reinterpret_cast<uint2*>(&Abf[(size_t)node * 128 + l * 4]) =
        make_uint2(pack2(acc.x, acc.y), pack2(acc.z, acc.w));
}

// ================= MFMA GEMM: out[N,128] = relu(A[N,128]bf16 @ Wt^T + b) in bf16 =================
__global__ __launch_bounds__(256) void gemm_mfma128(const unsigned short* __restrict__ Abf,
                                                    const unsigned short* __restrict__ Wt,
                                                    const float* __restrict__ bias,
                                                    unsigned short* __restrict__ out, int N) {
    constexpr int LDW = 136;  // ushort pitch (272B, 16B-aligned)
    __shared__ unsigned short As[64 * LDW];
    __shared__ unsigned short Ws[128 * LDW];
    __shared__ float bs[128];

    const int tid = threadIdx.x;
    const int n0 = blockIdx.x * 64;

#pragma unroll
    for (int i = 0; i < 4; ++i) {
        int idx = tid + i * 256;
        int row = idx >> 4, c = idx & 15;
        int n = n0 + row;
        uint4 v = make_uint4(0u, 0u, 0u, 0u);
        if (n < N) v = *reinterpret_cast<const uint4*>(&Abf[(size_t)n * 128 + c * 8]);
        *reinterpret_cast<uint4*>(&As[row * LDW + c * 8]) = v;
    }
#pragma unroll
    for (int i = 0; i < 8; ++i) {
        int idx = tid + i * 256;
        int row = idx >> 4, c = idx & 15;
        uint4 v = *reinterpret_cast<const uint4*>(&Wt[(size_t)row * 128 + c * 8]);
        *reinterpret_cast<uint4*>(&Ws[row * LDW + c * 8]) = v;
    }
    if (tid < 128) bs[tid] = bias[tid];
    __syncthreads();

    const int w = tid >> 6, l = tid & 63;
    const int wr = w >> 1, wc = w & 1;
    const int r = l & 15, g = l >> 4;

    f32x4 acc[2][4];
#pragma unroll
    for (int rt = 0; rt < 2; ++rt)
#pragma unroll
        for (int ct = 0; ct < 4; ++ct) {
            float b = bs[wc * 64 + ct * 16 + r];
            acc[rt][ct] = (f32x4){b, b, b, b};
        }

#pragma unroll
    for (int s = 0; s < 4; ++s) {
        bf16x8 af[2], bfr[4];
#pragma unroll
        for (int rt = 0; rt < 2; ++rt)
            af[rt] = *reinterpret_cast<const bf16x8*>(
                &As[(wr * 32 + rt * 16 + r) * LDW + s * 32 + g * 8]);
#pragma unroll
        for (int ct = 0; ct < 4; ++ct)
            bfr[ct] = *reinterpret_cast<const bf16x8*>(
                &Ws[(wc * 64 + ct * 16 + r) * LDW + s * 32 + g * 8]);
#pragma unroll
        for (int rt = 0; rt < 2; ++rt)
#pragma unroll
            for (int ct = 0; ct < 4; ++ct)
                acc[rt][ct] = __builtin_amdgcn_mfma_f32_16x16x32_bf16(
                    af[rt], bfr[ct], acc[rt][ct], 0, 0, 0);
    }

#pragma unroll
    for (int rt = 0; rt < 2; ++rt) {
#pragma unroll
        for (int reg = 0; reg < 4; ++reg) {
            int n = n0 + wr * 32 + rt * 16 + 4 * g + reg;
            if (n < N) {
#pragma unroll
                for (int ct = 0; ct < 4; ++ct) {
                    int j = wc * 64 + ct * 16 + r;
                    float v = fmaxf(acc[rt][ct][reg], 0.f);
                    out[(size_t)n * 128 + j] = f2bf(v);
                }
            }
        }
    }
}

// ================= MFMA GEMM: Tb[N,40]bf16 = H1[N,128]bf16 @ W2a (no bias/relu) =================
__global__ __launch_bounds__(256) void gemm_t2_mfma(const unsigned short* __restrict__ Abf,
                                                    const unsigned short* __restrict__ Wt,
                                                    unsigned short* __restrict__ Tb, int N) {
    constexpr int LDW = 136;
    __shared__ unsigned short As[64 * LDW];
    __shared__ unsigned short Ws[48 * LDW];

    const int tid = threadIdx.x;
    const int n0 = blockIdx.x * 64;

#pragma unroll
    for (int i = 0; i < 4; ++i) {
        int idx = tid + i * 256;
        int row = idx >> 4, c = idx & 15;
        int n = n0 + row;
        uint4 v = make_uint4(0u, 0u, 0u, 0u);
        if (n < N) v = *reinterpret_cast<const uint4*>(&Abf[(size_t)n * 128 + c * 8]);
        *reinterpret_cast<uint4*>(&As[row * LDW + c * 8]) = v;
    }
#pragma unroll
    for (int i = 0; i < 3; ++i) {
        int idx = tid + i * 256;
        int row = idx >> 4, c = idx & 15;
        uint4 v = *reinterpret_cast<const uint4*>(&Wt[(size_t)row * 128 + c * 8]);
        *reinterpret_cast<uint4*>(&Ws[row * LDW + c * 8]) = v;
    }
    __syncthreads();

    const int w = tid >> 6, l = tid & 63;
    const int r = l & 15, g = l >> 4;

    f32x4 acc[3] = {(f32x4){0,0,0,0}, (f32x4){0,0,0,0}, (f32x4){0,0,0,0}};

#pragma unroll
    for (int s = 0; s < 4; ++s) {
        bf16x8 af = *reinterpret_cast<const bf16x8*>(
            &As[(w * 16 + r) * LDW + s * 32 + g * 8]);
        bf16x8 bfr[3];
#pragma unroll
        for (int ct = 0; ct < 3; ++ct)
            bfr[ct] = *reinterpret_cast<const bf16x8*>(
                &Ws[(ct * 16 + r) * LDW + s * 32 + g * 8]);
#pragma unroll
        for (int ct = 0; ct < 3; ++ct)
            acc[ct] = __builtin_amdgcn_mfma_f32_16x16x32_bf16(af, bfr[ct], acc[ct], 0, 0, 0);
    }

#pragma unroll
    for (int reg = 0; reg < 4; ++reg) {
        int n = n0 + w * 16 + 4 * g + reg;
        if (n < N) {
#pragma unroll
            for (int ct = 0; ct < 3; ++ct) {
                int j = ct * 16 + r;
                if (j < OUTC) Tb[(size_t)n * OUTC + j] = f2bf(acc[ct][reg]);
            }
        }
    }
}

// ================= 40-dim aggregation: bf16 gather + bf16 self, fp32 acc =================
__global__ __launch_bounds__(256) void agg40_bf(const uint2* __restrict__ Tbf,
                                                const int* __restrict__ offs,
                                                const unsigned short* __restrict__ csr,
                                                float4* __restrict__ U, int N) {
    int wave = threadIdx.x >> 6;
    int lane = threadIdx.x & 63;
    int g = lane / 10;
    int sub = lane - g * 10;
    int node = blockIdx.x * 24 + wave * 6 + g;
    if (g >= 6 || node >= N) return;
    int s = offs[node], e = offs[node + 1];
    float4 acc = bf4(Tbf[(size_t)node * 10 + sub]);
    int i = s;
    for (; i + 8 <= e; i += 8) {
        int n0 = (int)__builtin_nontemporal_load(&csr[i + 0]);
        int n1 = (int)__builtin_nontemporal_load(&csr[i + 1]);
        int n2 = (int)__builtin_nontemporal_load(&csr[i + 2]);
        int n3 = (int)__builtin_nontemporal_load(&csr[i + 3]);
        int n4 = (int)__builtin_nontemporal_load(&csr[i + 4]);
        int n5 = (int)__builtin_nontemporal_load(&csr[i + 5]);
        int n6 = (int)__builtin_nontemporal_load(&csr[i + 6]);
        int n7 = (int)__builtin_nontemporal_load(&csr[i + 7]);
        float4 v0 = bf4(Tbf[(size_t)n0 * 10 + sub]);
        float4 v1 = bf4(Tbf[(size_t)n1 * 10 + sub]);
        float4 v2 = bf4(Tbf[(size_t)n2 * 10 + sub]);
        float4 v3 = bf4(Tbf[(size_t)n3 * 10 + sub]);
        float4 v4 = bf4(Tbf[(size_t)n4 * 10 + sub]);
        float4 v5 = bf4(Tbf[(size_t)n5 * 10 + sub]);
        float4 v6 = bf4(Tbf[(size_t)n6 * 10 + sub]);
        float4 v7 = bf4(Tbf[(size_t)n7 * 10 + sub]);
        acc.x += ((v0.x + v1.x) + (v2.x + v3.x)) + ((v4.x + v5.x) + (v6.x + v7.x));
        acc.y += ((v0.y + v1.y) + (v2.y + v3.y)) + ((v4.y + v5.y) + (v6.y + v7.y));
        acc.z += ((v0.z + v1.z) + (v2.z + v3.z)) + ((v4.z + v5.z) + (v6.z + v7.z));
        acc.w += ((v0.w + v1.w) + (v2.w + v3.w)) + ((v4.w + v5.w) + (v6.w + v7.w));
    }
    for (; i + 4 <= e; i += 4) {
        int n0 = (int)__builtin_nontemporal_load(&csr[i + 0]);
        int n1 = (int)__builtin_nontemporal_load(&csr[i + 1]);
        int n2 = (int)__builtin_nontemporal_load(&csr[i + 2]);
        int n3 = (int)__builtin_nontemporal_load(&csr[i + 3]);
        float4 v0 = bf4(Tbf[(size_t)n0 * 10 + sub]);
        float4 v1 = bf4(Tbf[(size_t)n1 * 10 + sub]);
        float4 v2 = bf4(Tbf[(size_t)n2 * 10 + sub]);
        float4 v3 = bf4(Tbf[(size_t)n3 * 10 + sub]);
        acc.x += (v0.x + v1.x) + (v2.x + v3.x);
        acc.y += (v0.y + v1.y) + (v2.y + v3.y);
        acc.z += (v0.z + v1.z) + (v2.z + v3.z);
        acc.w += (v0.w + v1.w) + (v2.w + v3.w);
    }
    for (; i < e; ++i) {
        int sn = (int)__builtin_nontemporal_load(&csr[i]);
        float4 v = bf4(Tbf[(size_t)sn * 10 + sub]);
        acc.x += v.x; acc.y += v.y; acc.z += v.z; acc.w += v.w;
    }
    U[(size_t)node * 10 + sub] = acc;
}

// ================= MFMA epilogue: logits = relu(U+b2a)bf16 @ W2b + b2b ; log_softmax =================
__global__ __launch_bounds__(256) void epi40_mfma(const float* __restrict__ U,
                                                  const float* __restrict__ b2a,
                                                  const unsigned short* __restrict__ Wt2b,
                                                  const float* __restrict__ b2b,
                                                  float* __restrict__ out, int N) {
    constexpr int LDW = 72;  // ushort pitch (144B, 16B-aligned)
    __shared__ unsigned short As[64 * LDW];
    __shared__ unsigned short Ws[48 * LDW];
    __shared__ float ba[40], bb[40];

    const int tid = threadIdx.x;
    const int n0 = blockIdx.x * 64;

    if (tid < 40) { ba[tid] = b2a[tid]; bb[tid] = b2b[tid]; }
    for (int idx = tid; idx < 384; idx += 256) {
        int row = idx >> 3, c = idx & 7;
        uint4 v = *reinterpret_cast<const uint4*>(&Wt2b[row * 64 + c * 8]);
        *reinterpret_cast<uint4*>(&Ws[row * LDW + c * 8]) = v;
    }
    __syncthreads();

    // stage A = bf16(relu(U + b2a)), cols 40..63 zero
    for (int idx = tid; idx < 64 * 8; idx += 256) {
        int row = idx >> 3, c8 = idx & 7;
        int n = n0 + row;
        uint4 o = make_uint4(0u, 0u, 0u, 0u);
        if (c8 < 5 && n < N) {
            int j = c8 * 8;
            float4 u0 = *reinterpret_cast<const float4*>(&U[(size_t)n * 40 + j]);
            float4 u1 = *reinterpret_cast<const float4*>(&U[(size_t)n * 40 + j + 4]);
            float t0 = fmaxf(u0.x + ba[j + 0], 0.f);
            float t1 = fmaxf(u0.y + ba[j + 1], 0.f);
            float t2 = fmaxf(u0.z + ba[j + 2], 0.f);
            float t3 = fmaxf(u0.w + ba[j + 3], 0.f);
            float t4 = fmaxf(u1.x + ba[j + 4], 0.f);
            float t5 = fmaxf(u1.y + ba[j + 5], 0.f);
            float t6 = fmaxf(u1.z + ba[j + 6], 0.f);
            float t7 = fmaxf(u1.w + ba[j + 7], 0.f);
            o = make_uint4(pack2(t0, t1), pack2(t2, t3), pack2(t4, t5), pack2(t6, t7));
        }
        *reinterpret_cast<uint4*>(&As[row * LDW + c8 * 8]) = o;
    }
    __syncthreads();

    const int w = tid >> 6, l = tid & 63;
    const int r = l & 15, g = l >> 4;

    f32x4 acc[3] = {(f32x4){0,0,0,0}, (f32x4){0,0,0,0}, (f32x4){0,0,0,0}};
#pragma unroll
    for (int s = 0; s < 2; ++s) {
        bf16x8 af = *reinterpret_cast<const bf16x8*>(
            &As[(w * 16 + r) * LDW + s * 32 + g * 8]);
#pragma unroll
        for (int ct = 0; ct < 3; ++ct) {
            bf16x8 bfr = *reinterpret_cast<const bf16x8*>(
                &Ws[(ct * 16 + r) * LDW + s * 32 + g * 8]);
            acc[ct] = __builtin_amdgcn_mfma_f32_16x16x32_bf16(af, bfr, acc[ct], 0, 0, 0);
        }
    }

    // D layout: row = w*16 + 4*g + reg, col = ct*16 + r. Row reduce across the 16-lane r-group.
    float bb0 = bb[r], bb1 = bb[16 + r], bb2 = (r < 8) ? bb[32 + r] : 0.f;
#pragma unroll
    for (int reg = 0; reg < 4; ++reg) {
        int n = n0 + w * 16 + 4 * g + reg;
        float lg0 = acc[0][reg] + bb0;
        float lg1 = acc[1][reg] + bb1;
        float lg2 = (r < 8) ? acc[2][reg] + bb2 : -INFINITY;
        float m = fmaxf(fmaxf(lg0, lg1), lg2);
#pragma unroll
        for (int off = 1; off < 16; off <<= 1) m = fmaxf(m, __shfl_xor(m, off));
        float s = expf(lg0 - m) + expf(lg1 - m) + ((r < 8) ? expf(lg2 - m) : 0.f);
#pragma unroll
        for (int off = 1; off < 16; off <<= 1) s += __shfl_xor(s, off);
        float lse = m + logf(s);
        if (n < N) {
            out[(size_t)n * OUTC + r] = lg0 - lse;
            out[(size_t)n * OUTC + 16 + r] = lg1 - lse;
            if (r < 8) out[(size_t)n * OUTC + 32 + r] = lg2 - lse;
        }
    }
}

// ================= launcher =================
extern "C" void kernel_launch(void* const* d_in, const int* in_sizes, int n_in,
                              void* d_out, int out_size, void* d_ws, size_t ws_size,
                              hipStream_t stream) {
    const float* x   = (const float*)d_in[0];
    const int* edges = (const int*)d_in[1];
    const float* W1a = (const float*)d_in[2];
    const float* b1a = (const float*)d_in[3];
    const float* W1b = (const float*)d_in[4];
    const float* b1b = (const float*)d_in[5];
    const float* W2a = (const float*)d_in[6];
    const float* b2a = (const float*)d_in[7];
    const float* W2b = (const float*)d_in[8];
    const float* b2b = (const float*)d_in[9];

    const int N = NNODES;
    const int E = in_sizes[1] / 2;
    const int* srcp = edges;
    const int* dstp = edges + E;

    auto au = [](size_t v) { return (v + 255) & ~(size_t)255; };
    char* p = (char*)d_ws;
    int* deg     = (int*)p; p += au((size_t)(N + 64) * 4);   // deg[N] + bcnt[8] (one memset)
    int* bcnt    = deg + N;
    int* offs    = (int*)p; p += au((size_t)(N + 1) * 4);
    int* cursor  = (int*)p; p += au((size_t)N * 4);
    int* lexcl   = (int*)p; p += au((size_t)N * 4);
    int* blksums = (int*)p; p += au((size_t)64 * 4);
    unsigned int*   pairs = (unsigned int*)p;  p += au((size_t)NBUCKET * CAP * 4);  // 6.4 MB
    unsigned short* csr   = (unsigned short*)p; p += au((size_t)E * 2);             // 1.6 MB
    unsigned int*   xh   = (unsigned int*)p;   p += au((size_t)N * INC * 2);
    unsigned short* Abf  = (unsigned short*)p; p += au((size_t)N * 128 * 2);
    unsigned short* X1bf = (unsigned short*)p; p += au((size_t)N * 128 * 2);
    unsigned short* H1bf = (unsigned short*)p; p += au((size_t)N * 128 * 2);
    unsigned short* Tb   = (unsigned short*)p; p += au((size_t)N * OUTC * 2);
    float*          bufU = (float*)p;          p += au((size_t)N * OUTC * 4);
    unsigned short* Wt1a = (unsigned short*)p; p += au((size_t)128 * 128 * 2);
    unsigned short* Wt1b = (unsigned short*)p; p += au((size_t)128 * 128 * 2);
    unsigned short* Wt2a = (unsigned short*)p; p += au((size_t)48 * 128 * 2);
    unsigned short* Wt2b = (unsigned short*)p; p += au((size_t)48 * 64 * 2);

    const int nb = (N + 1023) / 1024;  // 49
    const int n2 = N * INC / 2;
    const int prep_total = n2 + 128 * 128 + 128 * 128 + 48 * 128 + 48 * 64;

    // ---- fused prep (independent of CSR chain)
    prep_all<<<(prep_total + 255) / 256, 256, 0, stream>>>(
        (const float2*)x, xh, n2, W1a, Wt1a, W1b, Wt1b, W2a, Wt2a, W2b, Wt2b);

    // ---- CSR build: count+bin -> scan -> bucket-local scatter
    hipMemsetAsync(deg, 0, (size_t)(N + 64) * sizeof(int), stream);
    bin_count<<<BIN_BLOCKS, 256, 0, stream>>>(srcp, dstp, deg, bcnt, pairs, E);
    scan_pass1<<<nb, 256, 0, stream>>>(deg, lexcl, blksums, N);
    scan_pass2<<<1, 64, 0, stream>>>(blksums, nb, offs + N);
    scan_pass3<<<(N + 255) / 256, 256, 0, stream>>>(lexcl, blksums, offs, cursor, N);
    scatter_pairs<<<NBUCKET * SB_CHUNKS, 256, 0, stream>>>(pairs, bcnt, cursor, csr);

    // ---- layer 1
    agg_wide_bf<<<(N + 7) / 8, 256, 0, stream>>>((const float4*)x, (const uint2*)xh,
                                                 offs, csr, Abf, N);
    gemm_mfma128<<<(N + 63) / 64, 256, 0, stream>>>(Abf, Wt1a, b1a, X1bf, N);
    gemm_mfma128<<<(N + 63) / 64, 256, 0, stream>>>(X1bf, Wt1b, b1b, H1bf, N);

    // ---- layer 2 (reassociated)
    gemm_t2_mfma<<<(N + 63) / 64, 256, 0, stream>>>(H1bf, Wt2a, Tb, N);
    agg40_bf<<<(N + 23) / 24, 256, 0, stream>>>((const uint2*)Tb, offs, csr,
                                                (float4*)bufU, N);
    epi40_mfma<<<(N + 63) / 64, 256, 0, stream>>>(bufU, b2a, Wt2b, b2b, (float*)d_out, N);
}

// Round 11
// 120.317 us; speedup vs baseline: 1.5056x; 1.5056x over previous
//
#include <hip/hip_runtime.h>

// ---------------- problem constants ----------------
#define NNODES 50000
#define INC 100
#define HIDC 128
#define OUTC 40
#define NB2 50          // CSR buckets
#define BSZ2 1000       // nodes per bucket (50*1000 = 50000 exactly)
#define CAP2 24000      // per-bucket pair capacity (mean 16000, sigma ~125)
#define BIN_BLOCKS 256

typedef short bf16x8 __attribute__((ext_vector_type(8)));
typedef float f32x4 __attribute__((ext_vector_type(4)));

// bf16 helpers (RNE pack, shift unpack)
__device__ __forceinline__ unsigned short f2bf(float f) {
    unsigned int u = __float_as_uint(f);
    unsigned int r = (u + 0x7FFFu + ((u >> 16) & 1u)) >> 16;
    return (unsigned short)r;
}
__device__ __forceinline__ unsigned int pack2(float a, float b) {
    return (unsigned int)f2bf(a) | ((unsigned int)f2bf(b) << 16);
}
__device__ __forceinline__ float4 bf4(uint2 a) {
    return make_float4(__uint_as_float(a.x << 16), __uint_as_float(a.x & 0xFFFF0000u),
                       __uint_as_float(a.y << 16), __uint_as_float(a.y & 0xFFFF0000u));
}

// ================= fused prep: x->bf16 + 4 weight transposes =================
__global__ __launch_bounds__(256) void prep_all(const float2* __restrict__ x2,
                                                unsigned int* __restrict__ xh, int n2,
                                                const float* __restrict__ W1a,
                                                unsigned short* __restrict__ Wt1a,
                                                const float* __restrict__ W1b,
                                                unsigned short* __restrict__ Wt1b,
                                                const float* __restrict__ W2a,
                                                unsigned short* __restrict__ Wt2a,
                                                const float* __restrict__ W2b,
                                                unsigned short* __restrict__ Wt2b) {
    int i = blockIdx.x * 256 + threadIdx.x;
    if (i < n2) {
        float2 v = x2[i];
        xh[i] = pack2(v.x, v.y);
        return;
    }
    i -= n2;
    if (i < 128 * 128) {  // Wt1a[j][128], W1a is [100][128]
        int j = i >> 7, k = i & 127;
        Wt1a[i] = f2bf((k < INC) ? W1a[k * HIDC + j] : 0.f);
        return;
    }
    i -= 128 * 128;
    if (i < 128 * 128) {  // Wt1b[j][128], W1b is [128][128]
        int j = i >> 7, k = i & 127;
        Wt1b[i] = f2bf(W1b[k * HIDC + j]);
        return;
    }
    i -= 128 * 128;
    if (i < 48 * 128) {  // Wt2a[j][128], W2a is [128][40]
        int j = i >> 7, k = i & 127;
        Wt2a[i] = f2bf((j < OUTC) ? W2a[k * OUTC + j] : 0.f);
        return;
    }
    i -= 48 * 128;
    if (i < 48 * 64) {  // Wt2b[j][64], W2b is [40][40]
        int j = i >> 6, k = i & 63;
        Wt2b[i] = f2bf((j < OUTC && k < OUTC) ? W2b[k * OUTC + j] : 0.f);
        return;
    }
}

// ================= bin pairs by bucket (LDS atomics per edge; 50 global atomics/block) =================
__global__ __launch_bounds__(256) void bin_pairs(const int* __restrict__ src,
                                                 const int* __restrict__ dst,
                                                 int* __restrict__ bcnt,
                                                 unsigned int* __restrict__ pairs, int E) {
    __shared__ int bcount[NB2];
    __shared__ int bbase[NB2];
    __shared__ int bpos[NB2];
    int t = threadIdx.x;
    if (t < NB2) bcount[t] = 0;
    __syncthreads();
    int lo = (int)((long long)E * blockIdx.x / BIN_BLOCKS);
    int hi = (int)((long long)E * (blockIdx.x + 1) / BIN_BLOCKS);
    for (int e = lo + t; e < hi; e += 256) {
        int d = dst[e];
        atomicAdd(&bcount[d / BSZ2], 1);   // LDS
    }
    __syncthreads();
    if (t < NB2) {
        bbase[t] = atomicAdd(&bcnt[t], bcount[t]);  // global, 50/block
        bpos[t] = 0;
    }
    __syncthreads();
    for (int e = lo + t; e < hi; e += 256) {
        int d = dst[e];
        int s = src[e];
        int b = d / BSZ2;
        int rk = atomicAdd(&bpos[b], 1);   // LDS
        pairs[(size_t)b * CAP2 + bbase[b] + rk] = ((unsigned int)d << 16) | (unsigned int)s;
    }
}

// ================= per-bucket CSR build fully in LDS (zero global atomics) =================
__global__ __launch_bounds__(1024) void build_bucket(const unsigned int* __restrict__ pairs,
                                                     const int* __restrict__ bcnt,
                                                     int* __restrict__ offs,
                                                     unsigned short* __restrict__ csr) {
    __shared__ int hist[BSZ2];
    __shared__ int cur[BSZ2];
    __shared__ int wsum[16];
    __shared__ unsigned short lcsr[CAP2];
    __shared__ int base_s;

    const int b = blockIdx.x;
    const int t = threadIdx.x;

    if (t == 0) {  // bucket base = sum of counts before b
        int s = 0;
        for (int j = 0; j < b; ++j) s += bcnt[j];
        base_s = s;
    }
    for (int i = t; i < BSZ2; i += 1024) hist[i] = 0;
    __syncthreads();

    const int cnt = bcnt[b];
    const unsigned int* P = pairs + (size_t)b * CAP2;
    const int nlo = b * BSZ2;

    for (int i = t; i < cnt; i += 1024)
        atomicAdd(&hist[(int)(P[i] >> 16) - nlo], 1);   // LDS
    __syncthreads();

    // exclusive scan of hist[0..BSZ2) (1000 < 1024 threads)
    {
        int v = (t < BSZ2) ? hist[t] : 0;
        int lane = t & 63, wv = t >> 6;
        int incl = v;
#pragma unroll
        for (int off = 1; off < 64; off <<= 1) {
            int u = __shfl_up(incl, off);
            if (lane >= off) incl += u;
        }
        if (lane == 63) wsum[wv] = incl;
        __syncthreads();
        if (t == 0) {
            int s = 0;
#pragma unroll
            for (int j = 0; j < 16; ++j) { int x = wsum[j]; wsum[j] = s; s += x; }
        }
        __syncthreads();
        int excl = incl - v + wsum[wv];
        if (t < BSZ2) {
            cur[t] = excl;
            offs[nlo + t] = base_s + excl;
        }
        if (b == NB2 - 1 && t == 0) offs[NNODES] = base_s + cnt;
    }
    __syncthreads();

    for (int i = t; i < cnt; i += 1024) {
        unsigned int pr = P[i];
        int ln = (int)(pr >> 16) - nlo;
        int pos = atomicAdd(&cur[ln], 1);   // LDS
        lcsr[pos] = (unsigned short)(pr & 0xFFFFu);
    }
    __syncthreads();

    // coalesced dump LDS -> global
    for (int i = t; i < cnt; i += 1024) csr[base_s + i] = lcsr[i];
}

// ================= layer-1 aggregation: bf16 gather, fp32 self+acc, bf16 out [N][128] padded =================
__global__ __launch_bounds__(256) void agg_wide_bf(const float4* __restrict__ self,
                                                   const uint2* __restrict__ featbf,
                                                   const int* __restrict__ offs,
                                                   const unsigned short* __restrict__ csr,
                                                   unsigned short* __restrict__ Abf, int N) {
    constexpr int C4 = 25;
    int node = blockIdx.x * 8 + (threadIdx.x >> 5);
    int l = threadIdx.x & 31;
    if (node >= N) return;
    if (l >= C4) {  // zero-pad cols 100..127
        *reinterpret_cast<uint2*>(&Abf[(size_t)node * 128 + l * 4]) = make_uint2(0u, 0u);
        return;
    }
    int s = offs[node], e = offs[node + 1];
    float4 acc = self[(size_t)node * C4 + l];
    int i = s;
    for (; i + 8 <= e; i += 8) {
        int n0 = (int)csr[i + 0];
        int n1 = (int)csr[i + 1];
        int n2 = (int)csr[i + 2];
        int n3 = (int)csr[i + 3];
        int n4 = (int)csr[i + 4];
        int n5 = (int)csr[i + 5];
        int n6 = (int)csr[i + 6];
        int n7 = (int)csr[i + 7];
        float4 v0 = bf4(featbf[(size_t)n0 * C4 + l]);
        float4 v1 = bf4(featbf[(size_t)n1 * C4 + l]);
        float4 v2 = bf4(featbf[(size_t)n2 * C4 + l]);
        float4 v3 = bf4(featbf[(size_t)n3 * C4 + l]);
        float4 v4 = bf4(featbf[(size_t)n4 * C4 + l]);
        float4 v5 = bf4(featbf[(size_t)n5 * C4 + l]);
        float4 v6 = bf4(featbf[(size_t)n6 * C4 + l]);
        float4 v7 = bf4(featbf[(size_t)n7 * C4 + l]);
        acc.x += ((v0.x + v1.x) + (v2.x + v3.x)) + ((v4.x + v5.x) + (v6.x + v7.x));
        acc.y += ((v0.y + v1.y) + (v2.y + v3.y)) + ((v4.y + v5.y) + (v6.y + v7.y));
        acc.z += ((v0.z + v1.z) + (v2.z + v3.z)) + ((v4.z + v5.z) + (v6.z + v7.z));
        acc.w += ((v0.w + v1.w) + (v2.w + v3.w)) + ((v4.w + v5.w) + (v6.w + v7.w));
    }
    for (; i + 4 <= e; i += 4) {
        int n0 = (int)csr[i + 0];
        int n1 = (int)csr[i + 1];
        int n2 = (int)csr[i + 2];
        int n3 = (int)csr[i + 3];
        float4 v0 = bf4(featbf[(size_t)n0 * C4 + l]);
        float4 v1 = bf4(featbf[(size_t)n1 * C4 + l]);
        float4 v2 = bf4(featbf[(size_t)n2 * C4 + l]);
        float4 v3 = bf4(featbf[(size_t)n3 * C4 + l]);
        acc.x += (v0.x + v1.x) + (v2.x + v3.x);
        acc.y += (v0.y + v1.y) + (v2.y + v3.y);
        acc.z += (v0.z + v1.z) + (v2.z + v3.z);
        acc.w += (v0.w + v1.w) + (v2.w + v3.w);
    }
    for (; i < e; ++i) {
        int sn = (int)csr[i];
        float4 v = bf4(featbf[(size_t)sn * C4 + l]);
        acc.x += v.x; acc.y += v.y; acc.z += v.z; acc.w += v.w;
    }
    *reinterpret_cast<uint2*>(&Abf[(size_t)node * 128 + l * 4]) =
        make_uint2(pack2(acc.x, acc.y), pack2(acc.z, acc.w));
}

// ================= MFMA GEMM: out[N,128] = relu(A[N,128]bf16 @ Wt^T + b) in bf16 =================
__global__ __launch_bounds__(256) void gemm_mfma128(const unsigned short* __restrict__ Abf,
                                                    const unsigned short* __restrict__ Wt,
                                                    const float* __restrict__ bias,
                                                    unsigned short* __restrict__ out, int N) {
    constexpr int LDW = 136;  // ushort pitch (272B, 16B-aligned)
    __shared__ unsigned short As[64 * LDW];
    __shared__ unsigned short Ws[128 * LDW];
    __shared__ float bs[128];

    const int tid = threadIdx.x;
    const int n0 = blockIdx.x * 64;

#pragma unroll
    for (int i = 0; i < 4; ++i) {
        int idx = tid + i * 256;
        int row = idx >> 4, c = idx & 15;
        int n = n0 + row;
        uint4 v = make_uint4(0u, 0u, 0u, 0u);
        if (n < N) v = *reinterpret_cast<const uint4*>(&Abf[(size_t)n * 128 + c * 8]);
        *reinterpret_cast<uint4*>(&As[row * LDW + c * 8]) = v;
    }
#pragma unroll
    for (int i = 0; i < 8; ++i) {
        int idx = tid + i * 256;
        int row = idx >> 4, c = idx & 15;
        uint4 v = *reinterpret_cast<const uint4*>(&Wt[(size_t)row * 128 + c * 8]);
        *reinterpret_cast<uint4*>(&Ws[row * LDW + c * 8]) = v;
    }
    if (tid < 128) bs[tid] = bias[tid];
    __syncthreads();

    const int w = tid >> 6, l = tid & 63;
    const int wr = w >> 1, wc = w & 1;
    const int r = l & 15, g = l >> 4;

    f32x4 acc[2][4];
#pragma unroll
    for (int rt = 0; rt < 2; ++rt)
#pragma unroll
        for (int ct = 0; ct < 4; ++ct) {
            float b = bs[wc * 64 + ct * 16 + r];
            acc[rt][ct] = (f32x4){b, b, b, b};
        }

#pragma unroll
    for (int s = 0; s < 4; ++s) {
        bf16x8 af[2], bfr[4];
#pragma unroll
        for (int rt = 0; rt < 2; ++rt)
            af[rt] = *reinterpret_cast<const bf16x8*>(
                &As[(wr * 32 + rt * 16 + r) * LDW + s * 32 + g * 8]);
#pragma unroll
        for (int ct = 0; ct < 4; ++ct)
            bfr[ct] = *reinterpret_cast<const bf16x8*>(
                &Ws[(wc * 64 + ct * 16 + r) * LDW + s * 32 + g * 8]);
#pragma unroll
        for (int rt = 0; rt < 2; ++rt)
#pragma unroll
            for (int ct = 0; ct < 4; ++ct)
                acc[rt][ct] = __builtin_amdgcn_mfma_f32_16x16x32_bf16(
                    af[rt], bfr[ct], acc[rt][ct], 0, 0, 0);
    }

#pragma unroll
    for (int rt = 0; rt < 2; ++rt) {
#pragma unroll
        for (int reg = 0; reg < 4; ++reg) {
            int n = n0 + wr * 32 + rt * 16 + 4 * g + reg;
            if (n < N) {
#pragma unroll
                for (int ct = 0; ct < 4; ++ct) {
                    int j = wc * 64 + ct * 16 + r;
                    float v = fmaxf(acc[rt][ct][reg], 0.f);
                    out[(size_t)n * 128 + j] = f2bf(v);
                }
            }
        }
    }
}

// ================= MFMA GEMM: Tb[N,40]bf16 = H1[N,128]bf16 @ W2a (no bias/relu) =================
__global__ __launch_bounds__(256) void gemm_t2_mfma(const unsigned short* __restrict__ Abf,
                                                    const unsigned short* __restrict__ Wt,
                                                    unsigned short* __restrict__ Tb, int N) {
    constexpr int LDW = 136;
    __shared__ unsigned short As[64 * LDW];
    __shared__ unsigned short Ws[48 * LDW];

    const int tid = threadIdx.x;
    const int n0 = blockIdx.x * 64;

#pragma unroll
    for (int i = 0; i < 4; ++i) {
        int idx = tid + i * 256;
        int row = idx >> 4, c = idx & 15;
        int n = n0 + row;
        uint4 v = make_uint4(0u, 0u, 0u, 0u);
        if (n < N) v = *reinterpret_cast<const uint4*>(&Abf[(size_t)n * 128 + c * 8]);
        *reinterpret_cast<uint4*>(&As[row * LDW + c * 8]) = v;
    }
#pragma unroll
    for (int i = 0; i < 3; ++i) {
        int idx = tid + i * 256;
        int row = idx >> 4, c = idx & 15;
        uint4 v = *reinterpret_cast<const uint4*>(&Wt[(size_t)row * 128 + c * 8]);
        *reinterpret_cast<uint4*>(&Ws[row * LDW + c * 8]) = v;
    }
    __syncthreads();

    const int w = tid >> 6, l = tid & 63;
    const int r = l & 15, g = l >> 4;

    f32x4 acc[3] = {(f32x4){0,0,0,0}, (f32x4){0,0,0,0}, (f32x4){0,0,0,0}};

#pragma unroll
    for (int s = 0; s < 4; ++s) {
        bf16x8 af = *reinterpret_cast<const bf16x8*>(
            &As[(w * 16 + r) * LDW + s * 32 + g * 8]);
        bf16x8 bfr[3];
#pragma unroll
        for (int ct = 0; ct < 3; ++ct)
            bfr[ct] = *reinterpret_cast<const bf16x8*>(
                &Ws[(ct * 16 + r) * LDW + s * 32 + g * 8]);
#pragma unroll
        for (int ct = 0; ct < 3; ++ct)
            acc[ct] = __builtin_amdgcn_mfma_f32_16x16x32_bf16(af, bfr[ct], acc[ct], 0, 0, 0);
    }

#pragma unroll
    for (int reg = 0; reg < 4; ++reg) {
        int n = n0 + w * 16 + 4 * g + reg;
        if (n < N) {
#pragma unroll
            for (int ct = 0; ct < 3; ++ct) {
                int j = ct * 16 + r;
                if (j < OUTC) Tb[(size_t)n * OUTC + j] = f2bf(acc[ct][reg]);
            }
        }
    }
}

// ================= 40-dim aggregation: bf16 gather + bf16 self, fp32 acc =================
__global__ __launch_bounds__(256) void agg40_bf(const uint2* __restrict__ Tbf,
                                                const int* __restrict__ offs,
                                                const unsigned short* __restrict__ csr,
                                                float4* __restrict__ U, int N) {
    int wave = threadIdx.x >> 6;
    int lane = threadIdx.x & 63;
    int g = lane / 10;
    int sub = lane - g * 10;
    int node = blockIdx.x * 24 + wave * 6 + g;
    if (g >= 6 || node >= N) return;
    int s = offs[node], e = offs[node + 1];
    float4 acc = bf4(Tbf[(size_t)node * 10 + sub]);
    int i = s;
    for (; i + 8 <= e; i += 8) {
        int n0 = (int)csr[i + 0];
        int n1 = (int)csr[i + 1];
        int n2 = (int)csr[i + 2];
        int n3 = (int)csr[i + 3];
        int n4 = (int)csr[i + 4];
        int n5 = (int)csr[i + 5];
        int n6 = (int)csr[i + 6];
        int n7 = (int)csr[i + 7];
        float4 v0 = bf4(Tbf[(size_t)n0 * 10 + sub]);
        float4 v1 = bf4(Tbf[(size_t)n1 * 10 + sub]);
        float4 v2 = bf4(Tbf[(size_t)n2 * 10 + sub]);
        float4 v3 = bf4(Tbf[(size_t)n3 * 10 + sub]);
        float4 v4 = bf4(Tbf[(size_t)n4 * 10 + sub]);
        float4 v5 = bf4(Tbf[(size_t)n5 * 10 + sub]);
        float4 v6 = bf4(Tbf[(size_t)n6 * 10 + sub]);
        float4 v7 = bf4(Tbf[(size_t)n7 * 10 + sub]);
        acc.x += ((v0.x + v1.x) + (v2.x + v3.x)) + ((v4.x + v5.x) + (v6.x + v7.x));
        acc.y += ((v0.y + v1.y) + (v2.y + v3.y)) + ((v4.y + v5.y) + (v6.y + v7.y));
        acc.z += ((v0.z + v1.z) + (v2.z + v3.z)) + ((v4.z + v5.z) + (v6.z + v7.z));
        acc.w += ((v0.w + v1.w) + (v2.w + v3.w)) + ((v4.w + v5.w) + (v6.w + v7.w));
    }
    for (; i + 4 <= e; i += 4) {
        int n0 = (int)csr[i + 0];
        int n1 = (int)csr[i + 1];
        int n2 = (int)csr[i + 2];
        int n3 = (int)csr[i + 3];
        float4 v0 = bf4(Tbf[(size_t)n0 * 10 + sub]);
        float4 v1 = bf4(Tbf[(size_t)n1 * 10 + sub]);
        float4 v2 = bf4(Tbf[(size_t)n2 * 10 + sub]);
        float4 v3 = bf4(Tbf[(size_t)n3 * 10 + sub]);
        acc.x += (v0.x + v1.x) + (v2.x + v3.x);
        acc.y += (v0.y + v1.y) + (v2.y + v3.y);
        acc.z += (v0.z + v1.z) + (v2.z + v3.z);
        acc.w += (v0.w + v1.w) + (v2.w + v3.w);
    }
    for (; i < e; ++i) {
        int sn = (int)csr[i];
        float4 v = bf4(Tbf[(size_t)sn * 10 + sub]);
        acc.x += v.x; acc.y += v.y; acc.z += v.z; acc.w += v.w;
    }
    U[(size_t)node * 10 + sub] = acc;
}

// ================= MFMA epilogue: logits = relu(U+b2a)bf16 @ W2b + b2b ; log_softmax =================
__global__ __launch_bounds__(256) void epi40_mfma(const float* __restrict__ U,
                                                  const float* __restrict__ b2a,
                                                  const unsigned short* __restrict__ Wt2b,
                                                  const float* __restrict__ b2b,
                                                  float* __restrict__ out, int N) {
    constexpr int LDW = 72;  // ushort pitch (144B, 16B-aligned)
    __shared__ unsigned short As[64 * LDW];
    __shared__ unsigned short Ws[48 * LDW];
    __shared__ float ba[40], bb[40];

    const int tid = threadIdx.x;
    const int n0 = blockIdx.x * 64;

    if (tid < 40) { ba[tid] = b2a[tid]; bb[tid] = b2b[tid]; }
    for (int idx = tid; idx < 384; idx += 256) {
        int row = idx >> 3, c = idx & 7;
        uint4 v = *reinterpret_cast<const uint4*>(&Wt2b[row * 64 + c * 8]);
        *reinterpret_cast<uint4*>(&Ws[row * LDW + c * 8]) = v;
    }
    __syncthreads();

    // stage A = bf16(relu(U + b2a)), cols 40..63 zero
    for (int idx = tid; idx < 64 * 8; idx += 256) {
        int row = idx >> 3, c8 = idx & 7;
        int n = n0 + row;
        uint4 o = make_uint4(0u, 0u, 0u, 0u);
        if (c8 < 5 && n < N) {
            int j = c8 * 8;
            float4 u0 = *reinterpret_cast<const float4*>(&U[(size_t)n * 40 + j]);
            float4 u1 = *reinterpret_cast<const float4*>(&U[(size_t)n * 40 + j + 4]);
            float t0 = fmaxf(u0.x + ba[j + 0], 0.f);
            float t1 = fmaxf(u0.y + ba[j + 1], 0.f);
            float t2 = fmaxf(u0.z + ba[j + 2], 0.f);
            float t3 = fmaxf(u0.w + ba[j + 3], 0.f);
            float t4 = fmaxf(u1.x + ba[j + 4], 0.f);
            float t5 = fmaxf(u1.y + ba[j + 5], 0.f);
            float t6 = fmaxf(u1.z + ba[j + 6], 0.f);
            float t7 = fmaxf(u1.w + ba[j + 7], 0.f);
            o = make_uint4(pack2(t0, t1), pack2(t2, t3), pack2(t4, t5), pack2(t6, t7));
        }
        *reinterpret_cast<uint4*>(&As[row * LDW + c8 * 8]) = o;
    }
    __syncthreads();

    const int w = tid >> 6, l = tid & 63;
    const int r = l & 15, g = l >> 4;

    f32x4 acc[3] = {(f32x4){0,0,0,0}, (f32x4){0,0,0,0}, (f32x4){0,0,0,0}};
#pragma unroll
    for (int s = 0; s < 2; ++s) {
        bf16x8 af = *reinterpret_cast<const bf16x8*>(
            &As[(w * 16 + r) * LDW + s * 32 + g * 8]);
#pragma unroll
        for (int ct = 0; ct < 3; ++ct) {
            bf16x8 bfr = *reinterpret_cast<const bf16x8*>(
                &Ws[(ct * 16 + r) * LDW + s * 32 + g * 8]);
            acc[ct] = __builtin_amdgcn_mfma_f32_16x16x32_bf16(af, bfr, acc[ct], 0, 0, 0);
        }
    }

    // D layout: row = w*16 + 4*g + reg, col = ct*16 + r. Row reduce across the 16-lane r-group.
    float bb0 = bb[r], bb1 = bb[16 + r], bb2 = (r < 8) ? bb[32 + r] : 0.f;
#pragma unroll
    for (int reg = 0; reg < 4; ++reg) {
        int n = n0 + w * 16 + 4 * g + reg;
        float lg0 = acc[0][reg] + bb0;
        float lg1 = acc[1][reg] + bb1;
        float lg2 = (r < 8) ? acc[2][reg] + bb2 : -INFINITY;
        float m = fmaxf(fmaxf(lg0, lg1), lg2);
#pragma unroll
        for (int off = 1; off < 16; off <<= 1) m = fmaxf(m, __shfl_xor(m, off));
        float s = expf(lg0 - m) + expf(lg1 - m) + ((r < 8) ? expf(lg2 - m) : 0.f);
#pragma unroll
        for (int off = 1; off < 16; off <<= 1) s += __shfl_xor(s, off);
        float lse = m + logf(s);
        if (n < N) {
            out[(size_t)n * OUTC + r] = lg0 - lse;
            out[(size_t)n * OUTC + 16 + r] = lg1 - lse;
            if (r < 8) out[(size_t)n * OUTC + 32 + r] = lg2 - lse;
        }
    }
}

// ================= launcher =================
extern "C" void kernel_launch(void* const* d_in, const int* in_sizes, int n_in,
                              void* d_out, int out_size, void* d_ws, size_t ws_size,
                              hipStream_t stream) {
    const float* x   = (const float*)d_in[0];
    const int* edges = (const int*)d_in[1];
    const float* W1a = (const float*)d_in[2];
    const float* b1a = (const float*)d_in[3];
    const float* W1b = (const float*)d_in[4];
    const float* b1b = (const float*)d_in[5];
    const float* W2a = (const float*)d_in[6];
    const float* b2a = (const float*)d_in[7];
    const float* W2b = (const float*)d_in[8];
    const float* b2b = (const float*)d_in[9];

    const int N = NNODES;
    const int E = in_sizes[1] / 2;
    const int* srcp = edges;
    const int* dstp = edges + E;

    auto au = [](size_t v) { return (v + 255) & ~(size_t)255; };
    char* p = (char*)d_ws;
    int* bcnt    = (int*)p; p += au((size_t)NB2 * 4);
    int* offs    = (int*)p; p += au((size_t)(N + 1) * 4);
    unsigned int*   pairs = (unsigned int*)p;  p += au((size_t)NB2 * CAP2 * 4);  // 4.8 MB
    unsigned short* csr   = (unsigned short*)p; p += au((size_t)E * 2);          // 1.6 MB
    unsigned int*   xh   = (unsigned int*)p;   p += au((size_t)N * INC * 2);
    unsigned short* Abf  = (unsigned short*)p; p += au((size_t)N * 128 * 2);
    unsigned short* X1bf = (unsigned short*)p; p += au((size_t)N * 128 * 2);
    unsigned short* H1bf = (unsigned short*)p; p += au((size_t)N * 128 * 2);
    unsigned short* Tb   = (unsigned short*)p; p += au((size_t)N * OUTC * 2);
    float*          bufU = (float*)p;          p += au((size_t)N * OUTC * 4);
    unsigned short* Wt1a = (unsigned short*)p; p += au((size_t)128 * 128 * 2);
    unsigned short* Wt1b = (unsigned short*)p; p += au((size_t)128 * 128 * 2);
    unsigned short* Wt2a = (unsigned short*)p; p += au((size_t)48 * 128 * 2);
    unsigned short* Wt2b = (unsigned short*)p; p += au((size_t)48 * 64 * 2);

    const int n2 = N * INC / 2;
    const int prep_total = n2 + 128 * 128 + 128 * 128 + 48 * 128 + 48 * 64;

    // ---- fused prep (independent of CSR chain)
    prep_all<<<(prep_total + 255) / 256, 256, 0, stream>>>(
        (const float2*)x, xh, n2, W1a, Wt1a, W1b, Wt1b, W2a, Wt2a, W2b, Wt2b);

    // ---- CSR build: bin (LDS atomics) -> per-bucket LDS build (no global atomics)
    hipMemsetAsync(bcnt, 0, (size_t)NB2 * sizeof(int), stream);
    bin_pairs<<<BIN_BLOCKS, 256, 0, stream>>>(srcp, dstp, bcnt, pairs, E);
    build_bucket<<<NB2, 1024, 0, stream>>>(pairs, bcnt, offs, csr);

    // ---- layer 1
    agg_wide_bf<<<(N + 7) / 8, 256, 0, stream>>>((const float4*)x, (const uint2*)xh,
                                                 offs, csr, Abf, N);
    gemm_mfma128<<<(N + 63) / 64, 256, 0, stream>>>(Abf, Wt1a, b1a, X1bf, N);
    gemm_mfma128<<<(N + 63) / 64, 256, 0, stream>>>(X1bf, Wt1b, b1b, H1bf, N);

    // ---- layer 2 (reassociated)
    gemm_t2_mfma<<<(N + 63) / 64, 256, 0, stream>>>(H1bf, Wt2a, Tb, N);
    agg40_bf<<<(N + 23) / 24, 256, 0, stream>>>((const uint2*)Tb, offs, csr,
                                                (float4*)bufU, N);
    epi40_mfma<<<(N + 63) / 64, 256, 0, stream>>>(bufU, b2a, Wt2b, b2b, (float*)d_out, N);
}

// Round 12
// 103.098 us; speedup vs baseline: 1.7571x; 1.1670x over previous
//
#include <hip/hip_runtime.h>

// ---------------- problem constants ----------------
#define NNODES 50000
#define INC 100
#define HIDC 128
#define OUTC 40
#define NB2 200         // CSR buckets
#define BSZ2 250        // nodes per bucket (200*250 = 50000 exactly)
#define CAP2 6400       // per-bucket pair capacity (mean 4000, sigma ~63 -> +38 sigma)
#define BIN_BLOCKS 256

typedef short bf16x8 __attribute__((ext_vector_type(8)));
typedef float f32x4 __attribute__((ext_vector_type(4)));

// bf16 helpers (RNE pack, shift unpack)
__device__ __forceinline__ unsigned short f2bf(float f) {
    unsigned int u = __float_as_uint(f);
    unsigned int r = (u + 0x7FFFu + ((u >> 16) & 1u)) >> 16;
    return (unsigned short)r;
}
__device__ __forceinline__ unsigned int pack2(float a, float b) {
    return (unsigned int)f2bf(a) | ((unsigned int)f2bf(b) << 16);
}
__device__ __forceinline__ float4 bf4(uint2 a) {
    return make_float4(__uint_as_float(a.x << 16), __uint_as_float(a.x & 0xFFFF0000u),
                       __uint_as_float(a.y << 16), __uint_as_float(a.y & 0xFFFF0000u));
}

// ================= fused prep: bcnt zero + x->bf16 + 4 weight transposes =================
__global__ __launch_bounds__(256) void prep_all(const float2* __restrict__ x2,
                                                unsigned int* __restrict__ xh, int n2,
                                                const float* __restrict__ W1a,
                                                unsigned short* __restrict__ Wt1a,
                                                const float* __restrict__ W1b,
                                                unsigned short* __restrict__ Wt1b,
                                                const float* __restrict__ W2a,
                                                unsigned short* __restrict__ Wt2a,
                                                const float* __restrict__ W2b,
                                                unsigned short* __restrict__ Wt2b,
                                                int* __restrict__ bcnt) {
    if (blockIdx.x == 0 && threadIdx.x < NB2) bcnt[threadIdx.x] = 0;
    int i = blockIdx.x * 256 + threadIdx.x;
    if (i < n2) {
        float2 v = x2[i];
        xh[i] = pack2(v.x, v.y);
        return;
    }
    i -= n2;
    if (i < 128 * 128) {  // Wt1a[j][128], W1a is [100][128]
        int j = i >> 7, k = i & 127;
        Wt1a[i] = f2bf((k < INC) ? W1a[k * HIDC + j] : 0.f);
        return;
    }
    i -= 128 * 128;
    if (i < 128 * 128) {  // Wt1b[j][128], W1b is [128][128]
        int j = i >> 7, k = i & 127;
        Wt1b[i] = f2bf(W1b[k * HIDC + j]);
        return;
    }
    i -= 128 * 128;
    if (i < 48 * 128) {  // Wt2a[j][128], W2a is [128][40]
        int j = i >> 7, k = i & 127;
        Wt2a[i] = f2bf((j < OUTC) ? W2a[k * OUTC + j] : 0.f);
        return;
    }
    i -= 48 * 128;
    if (i < 48 * 64) {  // Wt2b[j][64], W2b is [40][40]
        int j = i >> 6, k = i & 63;
        Wt2b[i] = f2bf((j < OUTC && k < OUTC) ? W2b[k * OUTC + j] : 0.f);
        return;
    }
}

// ================= bin pairs by bucket (LDS atomics per edge; 200 global atomics/block) =================
__global__ __launch_bounds__(256) void bin_pairs(const int* __restrict__ src,
                                                 const int* __restrict__ dst,
                                                 int* __restrict__ bcnt,
                                                 unsigned int* __restrict__ pairs, int E) {
    __shared__ int bcount[NB2];
    __shared__ int bbase[NB2];
    __shared__ int bpos[NB2];
    int t = threadIdx.x;
    if (t < NB2) bcount[t] = 0;
    __syncthreads();
    int lo = (int)((long long)E * blockIdx.x / BIN_BLOCKS);
    int hi = (int)((long long)E * (blockIdx.x + 1) / BIN_BLOCKS);
    for (int e = lo + t; e < hi; e += 256) {
        int d = dst[e];
        atomicAdd(&bcount[d / BSZ2], 1);   // LDS
    }
    __syncthreads();
    if (t < NB2) {
        bbase[t] = atomicAdd(&bcnt[t], bcount[t]);  // global, 200/block
        bpos[t] = 0;
    }
    __syncthreads();
    for (int e = lo + t; e < hi; e += 256) {
        int d = dst[e];
        int s = src[e];
        int b = d / BSZ2;
        int rk = atomicAdd(&bpos[b], 1);   // LDS
        pairs[(size_t)b * CAP2 + bbase[b] + rk] = ((unsigned int)d << 16) | (unsigned int)s;
    }
}

// ================= per-bucket CSR build fully in LDS (zero global atomics) =================
__global__ __launch_bounds__(256) void build_bucket(const unsigned int* __restrict__ pairs,
                                                    const int* __restrict__ bcnt,
                                                    int* __restrict__ offs,
                                                    unsigned short* __restrict__ csr) {
    __shared__ int hist[BSZ2];
    __shared__ int cur[BSZ2];
    __shared__ int wsum[4];
    __shared__ int redbuf[4];
    __shared__ unsigned short lcsr[CAP2];
    __shared__ int base_s;

    const int b = blockIdx.x;
    const int t = threadIdx.x;
    const int lane = t & 63, wv = t >> 6;

    // parallel base_s = sum_{j<b} bcnt[j]
    {
        int v = (t < b) ? bcnt[t] : 0;   // b <= 199 < 256
#pragma unroll
        for (int off = 32; off; off >>= 1) v += __shfl_xor(v, off);
        if (lane == 0) redbuf[wv] = v;
    }
    if (t < BSZ2) hist[t] = 0;
    __syncthreads();
    if (t == 0) base_s = redbuf[0] + redbuf[1] + redbuf[2] + redbuf[3];

    const int cnt = bcnt[b];
    const unsigned int* P = pairs + (size_t)b * CAP2;
    const int nlo = b * BSZ2;
    __syncthreads();

    for (int i = t; i < cnt; i += 256)
        atomicAdd(&hist[(int)(P[i] >> 16) - nlo], 1);   // LDS
    __syncthreads();

    // exclusive scan of hist[0..BSZ2) (250 < 256 threads)
    {
        int v = (t < BSZ2) ? hist[t] : 0;
        int incl = v;
#pragma unroll
        for (int off = 1; off < 64; off <<= 1) {
            int u = __shfl_up(incl, off);
            if (lane >= off) incl += u;
        }
        if (lane == 63) wsum[wv] = incl;
        __syncthreads();
        int wbase = 0;
#pragma unroll
        for (int j = 0; j < 4; ++j)
            if (j < wv) wbase += wsum[j];
        int excl = wbase + incl - v;
        if (t < BSZ2) {
            cur[t] = excl;
            offs[nlo + t] = base_s + excl;
        }
        if (b == NB2 - 1 && t == 0) offs[NNODES] = base_s + cnt;
    }
    __syncthreads();

    for (int i = t; i < cnt; i += 256) {
        unsigned int pr = P[i];
        int pos = atomicAdd(&cur[(int)(pr >> 16) - nlo], 1);   // LDS
        lcsr[pos] = (unsigned short)(pr & 0xFFFFu);
    }
    __syncthreads();

    // coalesced dump LDS -> global
    for (int i = t; i < cnt; i += 256) csr[base_s + i] = lcsr[i];
}

// ================= layer-1 aggregation: bf16 gather, fp32 self+acc, bf16 out [N][128] padded =================
__global__ __launch_bounds__(256) void agg_wide_bf(const float4* __restrict__ self,
                                                   const uint2* __restrict__ featbf,
                                                   const int* __restrict__ offs,
                                                   const unsigned short* __restrict__ csr,
                                                   unsigned short* __restrict__ Abf, int N) {
    constexpr int C4 = 25;
    int node = blockIdx.x * 8 + (threadIdx.x >> 5);
    int l = threadIdx.x & 31;
    if (node >= N) return;
    if (l >= C4) {  // zero-pad cols 100..127
        *reinterpret_cast<uint2*>(&Abf[(size_t)node * 128 + l * 4]) = make_uint2(0u, 0u);
        return;
    }
    int s = offs[node], e = offs[node + 1];
    float4 acc = self[(size_t)node * C4 + l];
    int i = s;
    for (; i + 8 <= e; i += 8) {
        int n0 = (int)csr[i + 0];
        int n1 = (int)csr[i + 1];
        int n2 = (int)csr[i + 2];
        int n3 = (int)csr[i + 3];
        int n4 = (int)csr[i + 4];
        int n5 = (int)csr[i + 5];
        int n6 = (int)csr[i + 6];
        int n7 = (int)csr[i + 7];
        float4 v0 = bf4(featbf[(size_t)n0 * C4 + l]);
        float4 v1 = bf4(featbf[(size_t)n1 * C4 + l]);
        float4 v2 = bf4(featbf[(size_t)n2 * C4 + l]);
        float4 v3 = bf4(featbf[(size_t)n3 * C4 + l]);
        float4 v4 = bf4(featbf[(size_t)n4 * C4 + l]);
        float4 v5 = bf4(featbf[(size_t)n5 * C4 + l]);
        float4 v6 = bf4(featbf[(size_t)n6 * C4 + l]);
        float4 v7 = bf4(featbf[(size_t)n7 * C4 + l]);
        acc.x += ((v0.x + v1.x) + (v2.x + v3.x)) + ((v4.x + v5.x) + (v6.x + v7.x));
        acc.y += ((v0.y + v1.y) + (v2.y + v3.y)) + ((v4.y + v5.y) + (v6.y + v7.y));
        acc.z += ((v0.z + v1.z) + (v2.z + v3.z)) + ((v4.z + v5.z) + (v6.z + v7.z));
        acc.w += ((v0.w + v1.w) + (v2.w + v3.w)) + ((v4.w + v5.w) + (v6.w + v7.w));
    }
    for (; i + 4 <= e; i += 4) {
        int n0 = (int)csr[i + 0];
        int n1 = (int)csr[i + 1];
        int n2 = (int)csr[i + 2];
        int n3 = (int)csr[i + 3];
        float4 v0 = bf4(featbf[(size_t)n0 * C4 + l]);
        float4 v1 = bf4(featbf[(size_t)n1 * C4 + l]);
        float4 v2 = bf4(featbf[(size_t)n2 * C4 + l]);
        float4 v3 = bf4(featbf[(size_t)n3 * C4 + l]);
        acc.x += (v0.x + v1.x) + (v2.x + v3.x);
        acc.y += (v0.y + v1.y) + (v2.y + v3.y);
        acc.z += (v0.z + v1.z) + (v2.z + v3.z);
        acc.w += (v0.w + v1.w) + (v2.w + v3.w);
    }
    for (; i < e; ++i) {
        int sn = (int)csr[i];
        float4 v = bf4(featbf[(size_t)sn * C4 + l]);
        acc.x += v.x; acc.y += v.y; acc.z += v.z; acc.w += v.w;
    }
    *reinterpret_cast<uint2*>(&Abf[(size_t)node * 128 + l * 4]) =
        make_uint2(pack2(acc.x, acc.y), pack2(acc.z, acc.w));
}

// ================= fused MLP: Abf -> relu(@W1a+b) -> relu(@W1b+b) -> @W2a -> Tb =================
// Intermediate tiles (X1, H1) live in LDS only (written back as bf16 — bit-identical to
// the previous global round-trip). Ws restaged per phase. 53 KB LDS -> 3 blocks/CU.
__global__ __launch_bounds__(256) void fused_mlp(const unsigned short* __restrict__ Abf,
                                                 const unsigned short* __restrict__ Wt1a,
                                                 const float* __restrict__ b1a,
                                                 const unsigned short* __restrict__ Wt1b,
                                                 const float* __restrict__ b1b,
                                                 const unsigned short* __restrict__ Wt2a,
                                                 unsigned short* __restrict__ Tb, int N) {
    constexpr int LDW = 136;
    __shared__ unsigned short As[64 * LDW];
    __shared__ unsigned short Ws[128 * LDW];
    __shared__ float bs1[128], bs2[128];

    const int tid = threadIdx.x;
    const int n0 = blockIdx.x * 64;

    // stage A tile + Wt1a + biases
#pragma unroll
    for (int i = 0; i < 4; ++i) {
        int idx = tid + i * 256;
        int row = idx >> 4, c = idx & 15;
        int n = n0 + row;
        uint4 v = make_uint4(0u, 0u, 0u, 0u);
        if (n < N) v = *reinterpret_cast<const uint4*>(&Abf[(size_t)n * 128 + c * 8]);
        *reinterpret_cast<uint4*>(&As[row * LDW + c * 8]) = v;
    }
#pragma unroll
    for (int i = 0; i < 8; ++i) {
        int idx = tid + i * 256;
        int row = idx >> 4, c = idx & 15;
        *reinterpret_cast<uint4*>(&Ws[row * LDW + c * 8]) =
            *reinterpret_cast<const uint4*>(&Wt1a[(size_t)row * 128 + c * 8]);
    }
    if (tid < 128) { bs1[tid] = b1a[tid]; bs2[tid] = b1b[tid]; }
    __syncthreads();

    const int w = tid >> 6, l = tid & 63;
    const int wr = w >> 1, wc = w & 1;
    const int r = l & 15, g = l >> 4;

    // ---- phase 1: X1 = relu(A @ W1a + b1a)
    f32x4 acc[2][4];
#pragma unroll
    for (int rt = 0; rt < 2; ++rt)
#pragma unroll
        for (int ct = 0; ct < 4; ++ct) {
            float b = bs1[wc * 64 + ct * 16 + r];
            acc[rt][ct] = (f32x4){b, b, b, b};
        }
#pragma unroll
    for (int s = 0; s < 4; ++s) {
        bf16x8 af[2], bfr[4];
#pragma unroll
        for (int rt = 0; rt < 2; ++rt)
            af[rt] = *reinterpret_cast<const bf16x8*>(
                &As[(wr * 32 + rt * 16 + r) * LDW + s * 32 + g * 8]);
#pragma unroll
        for (int ct = 0; ct < 4; ++ct)
            bfr[ct] = *reinterpret_cast<const bf16x8*>(
                &Ws[(wc * 64 + ct * 16 + r) * LDW + s * 32 + g * 8]);
#pragma unroll
        for (int rt = 0; rt < 2; ++rt)
#pragma unroll
            for (int ct = 0; ct < 4; ++ct)
                acc[rt][ct] = __builtin_amdgcn_mfma_f32_16x16x32_bf16(
                    af[rt], bfr[ct], acc[rt][ct], 0, 0, 0);
    }
    __syncthreads();  // all phase-1 LDS reads done

    // write X1 -> As (bf16), restage Ws <- Wt1b
#pragma unroll
    for (int rt = 0; rt < 2; ++rt)
#pragma unroll
        for (int reg = 0; reg < 4; ++reg) {
            int row = wr * 32 + rt * 16 + 4 * g + reg;
#pragma unroll
            for (int ct = 0; ct < 4; ++ct) {
                int col = wc * 64 + ct * 16 + r;
                As[row * LDW + col] = f2bf(fmaxf(acc[rt][ct][reg], 0.f));
            }
        }
#pragma unroll
    for (int i = 0; i < 8; ++i) {
        int idx = tid + i * 256;
        int row = idx >> 4, c = idx & 15;
        *reinterpret_cast<uint4*>(&Ws[row * LDW + c * 8]) =
            *reinterpret_cast<const uint4*>(&Wt1b[(size_t)row * 128 + c * 8]);
    }
    __syncthreads();

    // ---- phase 2: H1 = relu(X1 @ W1b + b1b)
#pragma unroll
    for (int rt = 0; rt < 2; ++rt)
#pragma unroll
        for (int ct = 0; ct < 4; ++ct) {
            float b = bs2[wc * 64 + ct * 16 + r];
            acc[rt][ct] = (f32x4){b, b, b, b};
        }
#pragma unroll
    for (int s = 0; s < 4; ++s) {
        bf16x8 af[2], bfr[4];
#pragma unroll
        for (int rt = 0; rt < 2; ++rt)
            af[rt] = *reinterpret_cast<const bf16x8*>(
                &As[(wr * 32 + rt * 16 + r) * LDW + s * 32 + g * 8]);
#pragma unroll
        for (int ct = 0; ct < 4; ++ct)
            bfr[ct] = *reinterpret_cast<const bf16x8*>(
                &Ws[(wc * 64 + ct * 16 + r) * LDW + s * 32 + g * 8]);
#pragma unroll
        for (int rt = 0; rt < 2; ++rt)
#pragma unroll
            for (int ct = 0; ct < 4; ++ct)
                acc[rt][ct] = __builtin_amdgcn_mfma_f32_16x16x32_bf16(
                    af[rt], bfr[ct], acc[rt][ct], 0, 0, 0);
    }
    __syncthreads();

    // write H1 -> As (bf16), restage Ws <- Wt2a (48 rows)
#pragma unroll
    for (int rt = 0; rt < 2; ++rt)
#pragma unroll
        for (int reg = 0; reg < 4; ++reg) {
            int row = wr * 32 + rt * 16 + 4 * g + reg;
#pragma unroll
            for (int ct = 0; ct < 4; ++ct) {
                int col = wc * 64 + ct * 16 + r;
                As[row * LDW + col] = f2bf(fmaxf(acc[rt][ct][reg], 0.f));
            }
        }
#pragma unroll
    for (int i = 0; i < 3; ++i) {
        int idx = tid + i * 256;
        int row = idx >> 4, c = idx & 15;
        *reinterpret_cast<uint4*>(&Ws[row * LDW + c * 8]) =
            *reinterpret_cast<const uint4*>(&Wt2a[(size_t)row * 128 + c * 8]);
    }
    __syncthreads();

    // ---- phase 3: T = H1 @ W2a  (4 waves x 16 rows, 3 col-tiles)
    f32x4 acc3[3] = {(f32x4){0, 0, 0, 0}, (f32x4){0, 0, 0, 0}, (f32x4){0, 0, 0, 0}};
#pragma unroll
    for (int s = 0; s < 4; ++s) {
        bf16x8 af = *reinterpret_cast<const bf16x8*>(
            &As[(w * 16 + r) * LDW + s * 32 + g * 8]);
#pragma unroll
        for (int ct = 0; ct < 3; ++ct) {
            bf16x8 bfr = *reinterpret_cast<const bf16x8*>(
                &Ws[(ct * 16 + r) * LDW + s * 32 + g * 8]);
            acc3[ct] = __builtin_amdgcn_mfma_f32_16x16x32_bf16(af, bfr, acc3[ct], 0, 0, 0);
        }
    }
#pragma unroll
    for (int reg = 0; reg < 4; ++reg) {
        int n = n0 + w * 16 + 4 * g + reg;
        if (n < N) {
#pragma unroll
            for (int ct = 0; ct < 3; ++ct) {
                int j = ct * 16 + r;
                if (j < OUTC) Tb[(size_t)n * OUTC + j] = f2bf(acc3[ct][reg]);
            }
        }
    }
}

// ================= 40-dim aggregation: bf16 gather + bf16 self, fp32 acc =================
__global__ __launch_bounds__(256) void agg40_bf(const uint2* __restrict__ Tbf,
                                                const int* __restrict__ offs,
                                                const unsigned short* __restrict__ csr,
                                                float4* __restrict__ U, int N) {
    int wave = threadIdx.x >> 6;
    int lane = threadIdx.x & 63;
    int g = lane / 10;
    int sub = lane - g * 10;
    int node = blockIdx.x * 24 + wave * 6 + g;
    if (g >= 6 || node >= N) return;
    int s = offs[node], e = offs[node + 1];
    float4 acc = bf4(Tbf[(size_t)node * 10 + sub]);
    int i = s;
    for (; i + 8 <= e; i += 8) {
        int n0 = (int)csr[i + 0];
        int n1 = (int)csr[i + 1];
        int n2 = (int)csr[i + 2];
        int n3 = (int)csr[i + 3];
        int n4 = (int)csr[i + 4];
        int n5 = (int)csr[i + 5];
        int n6 = (int)csr[i + 6];
        int n7 = (int)csr[i + 7];
        float4 v0 = bf4(Tbf[(size_t)n0 * 10 + sub]);
        float4 v1 = bf4(Tbf[(size_t)n1 * 10 + sub]);
        float4 v2 = bf4(Tbf[(size_t)n2 * 10 + sub]);
        float4 v3 = bf4(Tbf[(size_t)n3 * 10 + sub]);
        float4 v4 = bf4(Tbf[(size_t)n4 * 10 + sub]);
        float4 v5 = bf4(Tbf[(size_t)n5 * 10 + sub]);
        float4 v6 = bf4(Tbf[(size_t)n6 * 10 + sub]);
        float4 v7 = bf4(Tbf[(size_t)n7 * 10 + sub]);
        acc.x += ((v0.x + v1.x) + (v2.x + v3.x)) + ((v4.x + v5.x) + (v6.x + v7.x));
        acc.y += ((v0.y + v1.y) + (v2.y + v3.y)) + ((v4.y + v5.y) + (v6.y + v7.y));
        acc.z += ((v0.z + v1.z) + (v2.z + v3.z)) + ((v4.z + v5.z) + (v6.z + v7.z));
        acc.w += ((v0.w + v1.w) + (v2.w + v3.w)) + ((v4.w + v5.w) + (v6.w + v7.w));
    }
    for (; i + 4 <= e; i += 4) {
        int n0 = (int)csr[i + 0];
        int n1 = (int)csr[i + 1];
        int n2 = (int)csr[i + 2];
        int n3 = (int)csr[i + 3];
        float4 v0 = bf4(Tbf[(size_t)n0 * 10 + sub]);
        float4 v1 = bf4(Tbf[(size_t)n1 * 10 + sub]);
        float4 v2 = bf4(Tbf[(size_t)n2 * 10 + sub]);
        float4 v3 = bf4(Tbf[(size_t)n3 * 10 + sub]);
        acc.x += (v0.x + v1.x) + (v2.x + v3.x);
        acc.y += (v0.y + v1.y) + (v2.y + v3.y);
        acc.z += (v0.z + v1.z) + (v2.z + v3.z);
        acc.w += (v0.w + v1.w) + (v2.w + v3.w);
    }
    for (; i < e; ++i) {
        int sn = (int)csr[i];
        float4 v = bf4(Tbf[(size_t)sn * 10 + sub]);
        acc.x += v.x; acc.y += v.y; acc.z += v.z; acc.w += v.w;
    }
    U[(size_t)node * 10 + sub] = acc;
}

// ================= MFMA epilogue: logits = relu(U+b2a)bf16 @ W2b + b2b ; log_softmax =================
__global__ __launch_bounds__(256) void epi40_mfma(const float* __restrict__ U,
                                                  const float* __restrict__ b2a,
                                                  const unsigned short* __restrict__ Wt2b,
                                                  const float* __restrict__ b2b,
                                                  float* __restrict__ out, int N) {
    constexpr int LDW = 72;  // ushort pitch (144B, 16B-aligned)
    __shared__ unsigned short As[64 * LDW];
    __shared__ unsigned short Ws[48 * LDW];
    __shared__ float ba[40], bb[40];

    const int tid = threadIdx.x;
    const int n0 = blockIdx.x * 64;

    if (tid < 40) { ba[tid] = b2a[tid]; bb[tid] = b2b[tid]; }
    for (int idx = tid; idx < 384; idx += 256) {
        int row = idx >> 3, c = idx & 7;
        uint4 v = *reinterpret_cast<const uint4*>(&Wt2b[row * 64 + c * 8]);
        *reinterpret_cast<uint4*>(&Ws[row * LDW + c * 8]) = v;
    }
    __syncthreads();

    // stage A = bf16(relu(U + b2a)), cols 40..63 zero
    for (int idx = tid; idx < 64 * 8; idx += 256) {
        int row = idx >> 3, c8 = idx & 7;
        int n = n0 + row;
        uint4 o = make_uint4(0u, 0u, 0u, 0u);
        if (c8 < 5 && n < N) {
            int j = c8 * 8;
            float4 u0 = *reinterpret_cast<const float4*>(&U[(size_t)n * 40 + j]);
            float4 u1 = *reinterpret_cast<const float4*>(&U[(size_t)n * 40 + j + 4]);
            float t0 = fmaxf(u0.x + ba[j + 0], 0.f);
            float t1 = fmaxf(u0.y + ba[j + 1], 0.f);
            float t2 = fmaxf(u0.z + ba[j + 2], 0.f);
            float t3 = fmaxf(u0.w + ba[j + 3], 0.f);
            float t4 = fmaxf(u1.x + ba[j + 4], 0.f);
            float t5 = fmaxf(u1.y + ba[j + 5], 0.f);
            float t6 = fmaxf(u1.z + ba[j + 6], 0.f);
            float t7 = fmaxf(u1.w + ba[j + 7], 0.f);
            o = make_uint4(pack2(t0, t1), pack2(t2, t3), pack2(t4, t5), pack2(t6, t7));
        }
        *reinterpret_cast<uint4*>(&As[row * LDW + c8 * 8]) = o;
    }
    __syncthreads();

    const int w = tid >> 6, l = tid & 63;
    const int r = l & 15, g = l >> 4;

    f32x4 acc[3] = {(f32x4){0, 0, 0, 0}, (f32x4){0, 0, 0, 0}, (f32x4){0, 0, 0, 0}};
#pragma unroll
    for (int s = 0; s < 2; ++s) {
        bf16x8 af = *reinterpret_cast<const bf16x8*>(
            &As[(w * 16 + r) * LDW + s * 32 + g * 8]);
#pragma unroll
        for (int ct = 0; ct < 3; ++ct) {
            bf16x8 bfr = *reinterpret_cast<const bf16x8*>(
                &Ws[(ct * 16 + r) * LDW + s * 32 + g * 8]);
            acc[ct] = __builtin_amdgcn_mfma_f32_16x16x32_bf16(af, bfr, acc[ct], 0, 0, 0);
        }
    }

    // D layout: row = w*16 + 4*g + reg, col = ct*16 + r. Row reduce across the 16-lane r-group.
    float bb0 = bb[r], bb1 = bb[16 + r], bb2 = (r < 8) ? bb[32 + r] : 0.f;
#pragma unroll
    for (int reg = 0; reg < 4; ++reg) {
        int n = n0 + w * 16 + 4 * g + reg;
        float lg0 = acc[0][reg] + bb0;
        float lg1 = acc[1][reg] + bb1;
        float lg2 = (r < 8) ? acc[2][reg] + bb2 : -INFINITY;
        float m = fmaxf(fmaxf(lg0, lg1), lg2);
#pragma unroll
        for (int off = 1; off < 16; off <<= 1) m = fmaxf(m, __shfl_xor(m, off));
        float s = expf(lg0 - m) + expf(lg1 - m) + ((r < 8) ? expf(lg2 - m) : 0.f);
#pragma unroll
        for (int off = 1; off < 16; off <<= 1) s += __shfl_xor(s, off);
        float lse = m + logf(s);
        if (n < N) {
            out[(size_t)n * OUTC + r] = lg0 - lse;
            out[(size_t)n * OUTC + 16 + r] = lg1 - lse;
            if (r < 8) out[(size_t)n * OUTC + 32 + r] = lg2 - lse;
        }
    }
}

// ================= launcher =================
extern "C" void kernel_launch(void* const* d_in, const int* in_sizes, int n_in,
                              void* d_out, int out_size, void* d_ws, size_t ws_size,
                              hipStream_t stream) {
    const float* x   = (const float*)d_in[0];
    const int* edges = (const int*)d_in[1];
    const float* W1a = (const float*)d_in[2];
    const float* b1a = (const float*)d_in[3];
    const float* W1b = (const float*)d_in[4];
    const float* b1b = (const float*)d_in[5];
    const float* W2a = (const float*)d_in[6];
    const float* b2a = (const float*)d_in[7];
    const float* W2b = (const float*)d_in[8];
    const float* b2b = (const float*)d_in[9];

    const int N = NNODES;
    const int E = in_sizes[1] / 2;
    const int* srcp = edges;
    const int* dstp = edges + E;

    auto au = [](size_t v) { return (v + 255) & ~(size_t)255; };
    char* p = (char*)d_ws;
    int* bcnt    = (int*)p; p += au((size_t)NB2 * 4);
    int* offs    = (int*)p; p += au((size_t)(N + 1) * 4);
    unsigned int*   pairs = (unsigned int*)p;  p += au((size_t)NB2 * CAP2 * 4);  // 5.12 MB
    unsigned short* csr   = (unsigned short*)p; p += au((size_t)E * 2);          // 1.6 MB
    unsigned int*   xh   = (unsigned int*)p;   p += au((size_t)N * INC * 2);
    unsigned short* Abf  = (unsigned short*)p; p += au((size_t)N * 128 * 2);
    unsigned short* Tb   = (unsigned short*)p; p += au((size_t)N * OUTC * 2);
    float*          bufU = (float*)p;          p += au((size_t)N * OUTC * 4);
    unsigned short* Wt1a = (unsigned short*)p; p += au((size_t)128 * 128 * 2);
    unsigned short* Wt1b = (unsigned short*)p; p += au((size_t)128 * 128 * 2);
    unsigned short* Wt2a = (unsigned short*)p; p += au((size_t)48 * 128 * 2);
    unsigned short* Wt2b = (unsigned short*)p; p += au((size_t)48 * 64 * 2);

    const int n2 = N * INC / 2;
    const int prep_total = n2 + 128 * 128 + 128 * 128 + 48 * 128 + 48 * 64;

    // ---- fused prep (zeroes bcnt; independent of edge stream)
    prep_all<<<(prep_total + 255) / 256, 256, 0, stream>>>(
        (const float2*)x, xh, n2, W1a, Wt1a, W1b, Wt1b, W2a, Wt2a, W2b, Wt2b, bcnt);

    // ---- CSR build: bin (LDS atomics) -> per-bucket LDS build (no global atomics)
    bin_pairs<<<BIN_BLOCKS, 256, 0, stream>>>(srcp, dstp, bcnt, pairs, E);
    build_bucket<<<NB2, 256, 0, stream>>>(pairs, bcnt, offs, csr);

    // ---- layer 1: aggregate then fused 3-GEMM MLP (-> T in one pass)
    agg_wide_bf<<<(N + 7) / 8, 256, 0, stream>>>((const float4*)x, (const uint2*)xh,
                                                 offs, csr, Abf, N);
    fused_mlp<<<(N + 63) / 64, 256, 0, stream>>>(Abf, Wt1a, b1a, Wt1b, b1b, Wt2a, Tb, N);

    // ---- layer 2 (reassociated)
    agg40_bf<<<(N + 23) / 24, 256, 0, stream>>>((const uint2*)Tb, offs, csr,
                                                (float4*)bufU, N);
    epi40_mfma<<<(N + 63) / 64, 256, 0, stream>>>(bufU, b2a, Wt2b, b2b, (float*)d_out, N);
}